// Round 1
// 1732.172 us; speedup vs baseline: 1.1788x; 1.1788x over previous
//
#include <hip/hip_runtime.h>
#include <cstdint>

#define HID 4096
#define SEQ 1024
#define B_REQ 4
#define NH 32
#define DH 128
#define RANK 16

typedef unsigned short u16;
typedef __attribute__((ext_vector_type(8))) short short8;
typedef __attribute__((ext_vector_type(8))) unsigned short us8;
typedef __attribute__((ext_vector_type(4))) float f32x4;

static __device__ __forceinline__ float bf2f(u16 u) {
  union { unsigned int i; float f; } v; v.i = ((unsigned int)u) << 16; return v.f;
}
static __device__ __forceinline__ u16 f2bf(float f) {
  union { float f; unsigned int i; } v; v.f = f;
  unsigned int r = v.i + 0x7FFFu + ((v.i >> 16) & 1u);  // RNE
  return (u16)(r >> 16);
}

template<typename T> struct io;
template<> struct io<u16> {
  static __device__ __forceinline__ float ld(const u16* p, size_t i) { return bf2f(p[i]); }
  static __device__ __forceinline__ void st(u16* p, size_t i, float v) { p[i] = f2bf(v); }
};
template<> struct io<float> {
  static __device__ __forceinline__ float ld(const float* p, size_t i) { return p[i]; }
  static __device__ __forceinline__ void st(float* p, size_t i, float v) { p[i] = v; }
};

static __device__ __forceinline__ void ld8f(const u16* p, float* o) {
  us8 v = *(const us8*)p;
#pragma unroll
  for (int i = 0; i < 8; i++) o[i] = bf2f(v[i]);
}
static __device__ __forceinline__ void ld8f(const float* p, float* o) {
  const float4* q = (const float4*)p;
  float4 a = q[0], b = q[1];
  o[0]=a.x; o[1]=a.y; o[2]=a.z; o[3]=a.w; o[4]=b.x; o[5]=b.y; o[6]=b.z; o[7]=b.w;
}

// ---------- dtype probe: bf16 weights never have exponent >= 0xC0; fp32 low halves do ----------
__global__ void detect_k(const u16* __restrict__ w, int* __restrict__ dflag) {
  if (threadIdx.x == 0 && blockIdx.x == 0) {
    int huge = 0;
    for (int i = 0; i < 2048; i++) {
      int e = (w[i] >> 7) & 0xFF;
      if (e >= 0xC0) huge++;
    }
    dflag[0] = (huge > 8) ? 1 : 0;   // 1 => inputs are float32
  }
}

// ---------- convert input matrix to bf16 (identity when already bf16) ----------
template<typename T>
__global__ __launch_bounds__(256) void convert_k(const int* __restrict__ fl, int want,
    const T* __restrict__ src, u16* __restrict__ dst, int n) {
  if (fl[0] != want) return;
  int stride = gridDim.x * blockDim.x;
  for (int i = blockIdx.x * blockDim.x + threadIdx.x; i < n; i += stride)
    dst[i] = f2bf(io<T>::ld(src, i));
}

// ---------- transpose 4096x4096: T[n][k] = bf16(W[k][n]) ----------
template<typename T>
__global__ __launch_bounds__(256) void transpose_k(const int* __restrict__ fl, int want,
    const T* __restrict__ W, u16* __restrict__ Tt) {
  if (fl[0] != want) return;
  __shared__ u16 st[64][68];
  int r0 = blockIdx.y * 64, c0 = blockIdx.x * 64;
  int t = threadIdx.x;
  int r = t >> 2, cb = (t & 3) * 16;
#pragma unroll
  for (int j = 0; j < 16; j++)
    st[r][cb + j] = f2bf(io<T>::ld(W, (size_t)(r0 + r) * HID + c0 + cb + j));
  __syncthreads();
#pragma unroll
  for (int j = 0; j < 4; j++) {
    int cw = cb + j*4;
    ushort4 v;
    v.x = st[cw+0][r]; v.y = st[cw+1][r]; v.z = st[cw+2][r]; v.w = st[cw+3][r];
    *(ushort4*)&Tt[(size_t)(c0 + r) * HID + r0 + cw] = v;
  }
}

// ---------- r[b,s,:] = x_row @ A_b  (K=4096, R=16). z selects A matrix. ----------
template<typename T>
__global__ __launch_bounds__(256) void lora_r_k(const int* __restrict__ fl, int want,
    const u16* __restrict__ X, const T* __restrict__ A0,
    const T* __restrict__ A1, const T* __restrict__ A2, float* __restrict__ R) {
  if (fl[0] != want) return;
  int s = blockIdx.x, b = blockIdx.y, m = blockIdx.z;
  const T* A = (m==0?A0: m==1?A1:A2) + (size_t)b * HID * RANK;
  const u16* x = X + (size_t)(b*SEQ + s) * HID;
  float* r = R + ((size_t)(m*B_REQ + b) * SEQ + s) * RANK;
  int t = threadIdx.x;
  int c = t >> 4;                       // d = c + 16*i  -> A idx = t + 256*i (coalesced)
  float acc = 0.f;
  for (int i = 0; i < 256; i++)
    acc += bf2f(x[c + 16*i]) * io<T>::ld(A, t + 256*i);
  __shared__ float red[256];
  red[t] = acc;
  __syncthreads();
  if (t < 16) {
    float sum = 0.f;
#pragma unroll
    for (int cc = 0; cc < 16; cc++) sum += red[cc*16 + t];
    r[t] = sum;
  }
}

// ---------- C(4096x4096) = A @ BT^T, A/BT bf16, C dtype TOUT. m97 structure. ----------
template<typename TOUT>
__global__ __launch_bounds__(256) void gemm_bt_k(const int* __restrict__ fl, int want,
    const u16* __restrict__ A, const u16* __restrict__ BT, TOUT* __restrict__ C) {
  if (want >= 0 && fl[0] != want) return;
  __shared__ u16 sA[128*32];
  __shared__ u16 sB[128*32];
  int tid = threadIdx.x, lane = tid & 63, wave = tid >> 6;
  int l15 = lane & 15, quad = lane >> 4;
  int wm = wave >> 1, wn = wave & 1;
  int m0 = blockIdx.x * 128, n0 = blockIdx.y * 128;
  f32x4 acc[4][4];
  f32x4 zero = {0.f,0.f,0.f,0.f};
#pragma unroll
  for (int i=0;i<4;i++)
#pragma unroll
    for (int j=0;j<4;j++) acc[i][j] = zero;
  const u16* gA = A  + (size_t)(m0 + wave*32 + (lane>>2)) * HID + (lane&3)*8;
  const u16* gB = BT + (size_t)(n0 + wave*32 + (lane>>2)) * HID + (lane&3)*8;
  u16* lA = sA + (wave*32)*32;
  u16* lB = sB + (wave*32)*32;
  for (int k0 = 0; k0 < HID; k0 += 32) {
    __syncthreads();
#pragma unroll
    for (int i = 0; i < 2; i++) {
      __builtin_amdgcn_global_load_lds(
          (const __attribute__((address_space(1))) void*)(gA + (size_t)i*16*HID + k0),
          (__attribute__((address_space(3))) void*)(lA + i*16*32), 16, 0, 0);
      __builtin_amdgcn_global_load_lds(
          (const __attribute__((address_space(1))) void*)(gB + (size_t)i*16*HID + k0),
          (__attribute__((address_space(3))) void*)(lB + i*16*32), 16, 0, 0);
    }
    __syncthreads();
    short8 af[4], bfr[4];
#pragma unroll
    for (int tm=0;tm<4;tm++) af[tm]  = *(const short8*)&sA[(wm*64 + tm*16 + l15)*32 + quad*8];
#pragma unroll
    for (int tn=0;tn<4;tn++) bfr[tn] = *(const short8*)&sB[(wn*64 + tn*16 + l15)*32 + quad*8];
#pragma unroll
    for (int tm=0;tm<4;tm++)
#pragma unroll
      for (int tn=0;tn<4;tn++)
        acc[tm][tn] = __builtin_amdgcn_mfma_f32_16x16x32_bf16(af[tm], bfr[tn], acc[tm][tn], 0, 0, 0);
  }
  int rb = m0 + wm*64 + quad*4;
  int cb = n0 + wn*64 + l15;
#pragma unroll
  for (int tm=0;tm<4;tm++)
#pragma unroll
    for (int tn=0;tn<4;tn++)
#pragma unroll
      for (int rr=0;rr<4;rr++)
        io<TOUT>::st(C, (size_t)(rb + tm*16 + rr) * HID + cb + tn*16, acc[tm][tn][rr]);
}

// ---------- in-place bf16: val = lin + r@B ; rope for kind 0,1 ; plain for kind 2 ----------
// block = 256 threads, 4 s-rows x 4096 cols. thread owns (head h, d0..d0+7) AND its
// rope partner (d0+64..d0+71) -> rope is thread-local, no LDS exchange.
// 4-row tiling amortizes the 16x4096 B read 4x (L2 traffic 3.2GB -> 0.8GB).
template<typename T>
__global__ __launch_bounds__(256) void lora_rope_k(const int* __restrict__ fl, int want,
    u16* __restrict__ Qb, u16* __restrict__ Kb, u16* __restrict__ Vb,
    const float* __restrict__ R,
    const T* __restrict__ Bq, const T* __restrict__ Bk, const T* __restrict__ Bv) {
  if (fl[0] != want) return;
  int s0 = blockIdx.x * 4;
  int z = blockIdx.y; int kind = z >> 2, b = z & 3;
  u16* Ob = kind==0?Qb: kind==1?Kb:Vb;
  const T* Bm = (kind==0?Bq: kind==1?Bk:Bv) + (size_t)b * RANK * HID;
  int t = threadIdx.x;
  int h = t >> 3, d0 = (t & 7) * 8;
  int col0 = h*DH + d0, col1 = col0 + 64;
  __shared__ float rr[4][RANK];
  if (t < 64)
    rr[t>>4][t&15] = R[((size_t)(kind*B_REQ + b) * SEQ + s0 + (t>>4)) * RANK + (t&15)];
  __syncthreads();
  float v0[4][8], v1[4][8];
  size_t base = (size_t)(b*SEQ + s0) * HID;
#pragma unroll
  for (int si = 0; si < 4; si++) {
    us8 a = *(const us8*)&Ob[base + (size_t)si*HID + col0];
    us8 c = *(const us8*)&Ob[base + (size_t)si*HID + col1];
#pragma unroll
    for (int i = 0; i < 8; i++) { v0[si][i] = bf2f(a[i]); v1[si][i] = bf2f(c[i]); }
  }
#pragma unroll 4
  for (int j = 0; j < RANK; j++) {
    float b0[8], b1[8];
    ld8f(Bm + (size_t)j*HID + col0, b0);
    ld8f(Bm + (size_t)j*HID + col1, b1);
#pragma unroll
    for (int si = 0; si < 4; si++) {
      float rj = rr[si][j];
#pragma unroll
      for (int i = 0; i < 8; i++) { v0[si][i] += rj*b0[i]; v1[si][i] += rj*b1[i]; }
    }
  }
  if (kind == 2) {
#pragma unroll
    for (int si = 0; si < 4; si++) {
      us8 a, c;
#pragma unroll
      for (int i = 0; i < 8; i++) { a[i] = f2bf(v0[si][i]); c[i] = f2bf(v1[si][i]); }
      *(us8*)&Ob[base + (size_t)si*HID + col0] = a;
      *(us8*)&Ob[base + (size_t)si*HID + col1] = c;
    }
    return;
  }
  float fr[8];
#pragma unroll
  for (int i = 0; i < 8; i++)
    fr[i] = exp2f((float)(d0 + i) * (-13.287712379549449f / 64.f));
#pragma unroll
  for (int si = 0; si < 4; si++) {
    float sa = (float)(s0 + si);
    us8 a, c;
#pragma unroll
    for (int i = 0; i < 8; i++) {
      float sn, cs;
      sincosf(sa * fr[i], &sn, &cs);
      a[i] = f2bf(v0[si][i]*cs - v1[si][i]*sn);
      c[i] = f2bf(v1[si][i]*cs + v0[si][i]*sn);
    }
    *(us8*)&Ob[base + (size_t)si*HID + col0] = a;
    *(us8*)&Ob[base + (size_t)si*HID + col1] = c;
  }
}

// ---------- V^T: VT[(b*NH+h)*DH + d][s] = V[b*SEQ+s][h*DH+d] ----------
__global__ __launch_bounds__(256) void vtrans_k(const u16* __restrict__ V, u16* __restrict__ VT) {
  int st = blockIdx.x, h = blockIdx.y, b = blockIdx.z;
  int s0 = st * 64;
  __shared__ u16 tmp[64][136];
  int t = threadIdx.x;
  int sr = t >> 2, c0 = (t & 3) * 32;
  const u16* vp = V + (size_t)(b*SEQ + s0 + sr) * HID + h*DH + c0;
#pragma unroll
  for (int j = 0; j < 4; j++)
    *(us8*)&tmp[sr][c0 + j*8] = *(const us8*)(vp + j*8);
  __syncthreads();
  int d = t >> 1, so = (t & 1) * 32;
  u16* op = VT + ((size_t)(b*NH + h) * DH + d) * SEQ + s0 + so;
#pragma unroll
  for (int j = 0; j < 4; j++) {
    us8 v;
#pragma unroll
    for (int i = 0; i < 8; i++) ((u16*)&v)[i] = tmp[so + j*8 + i][d];
    *(us8*)(op + j*8) = v;
  }
}

// ---------- flash attention: block = (b, h, 64 q rows), 4 waves x 16 q rows, KVBLK=64 ----------
// qb reversed (heavy blocks dispatch first -> no 16x tail imbalance).
// sK [64][136]: bank-quad = (k + 4c + quad) mod 8 -> conflict-free b128 r/w.
// sVT [128][72] from pre-transposed V: coalesced us8 row staging, odd*8 stride conflict-free.
__global__ __launch_bounds__(256) void attn_k(
    const u16* __restrict__ Q, const u16* __restrict__ K, const u16* __restrict__ VT,
    u16* __restrict__ O) {
  int qb = (int)gridDim.x - 1 - (int)blockIdx.x;
  int h = blockIdx.y, b = blockIdx.z;
  int q0 = qb * 64;
  int tid = threadIdx.x, lane = tid & 63, wave = tid >> 6;
  int l15 = lane & 15, quad = lane >> 4;
  __shared__ u16 sK[64*136];
  __shared__ u16 sVT[128*72];
  __shared__ u16 sP[4][16*72];
  short8 qf[4];
  {
    const u16* qp = Q + (size_t)(b*SEQ + q0 + wave*16 + l15) * HID + h*DH + quad*8;
#pragma unroll
    for (int c = 0; c < 4; c++) qf[c] = *(const short8*)(qp + c*32);
  }
  f32x4 zero = {0.f,0.f,0.f,0.f};
  f32x4 oacc[8];
#pragma unroll
  for (int i=0;i<8;i++) oacc[i] = zero;
  float m_i[4], l_i[4];
#pragma unroll
  for (int r=0;r<4;r++){ m_i[r] = -1e30f; l_i[r] = 0.f; }
  int krow = tid >> 2, kcol = (tid & 3) * 32;
  int vrow = tid >> 1, vcol = (tid & 1) * 32;
  const u16* kbase = K + (size_t)(b*SEQ) * HID + h*DH;
  const u16* vbase = VT + (size_t)(b*NH + h) * DH * SEQ;
  int nkt = qb + 1;
  for (int kt = 0; kt < nkt; kt++) {
    int k0 = kt * 64;
    __syncthreads();
    {
      const u16* kp = kbase + (size_t)(k0 + krow) * HID + kcol;
#pragma unroll
      for (int j = 0; j < 4; j++)
        *(us8*)&sK[krow*136 + kcol + j*8] = *(const us8*)(kp + j*8);
      const u16* vp = vbase + (size_t)vrow * SEQ + k0 + vcol;
#pragma unroll
      for (int j = 0; j < 4; j++)
        *(us8*)&sVT[vrow*72 + vcol + j*8] = *(const us8*)(vp + j*8);
    }
    __syncthreads();
    int q_hi = q0 + wave*16 + 15;
    if (k0 <= q_hi) {
      f32x4 sc4[4];
#pragma unroll
      for (int g=0;g<4;g++) sc4[g] = zero;
#pragma unroll
      for (int c = 0; c < 4; c++) {
#pragma unroll
        for (int g = 0; g < 4; g++) {
          short8 kf = *(const short8*)&sK[(g*16 + l15)*136 + c*32 + quad*8];
          sc4[g] = __builtin_amdgcn_mfma_f32_16x16x32_bf16(qf[c], kf, sc4[g], 0,0,0);
        }
      }
      const float scale = 0.08838834764831845f;   // 1/sqrt(128)
      float alpha[4], pst[4][4];
#pragma unroll
      for (int r = 0; r < 4; r++) {
        int q_abs = q0 + wave*16 + quad*4 + r;
        float v[4];
#pragma unroll
        for (int g = 0; g < 4; g++) {
          v[g] = sc4[g][r] * scale;
          if (k0 + g*16 + l15 > q_abs) v[g] = -1e30f;
        }
        float mx = fmaxf(fmaxf(v[0],v[1]), fmaxf(v[2],v[3]));
#pragma unroll
        for (int sh = 1; sh < 16; sh <<= 1) mx = fmaxf(mx, __shfl_xor(mx, sh, 64));
        float mnew = fmaxf(m_i[r], mx);
        float a = __expf(m_i[r] - mnew);
        float rs = 0.f;
#pragma unroll
        for (int g = 0; g < 4; g++) { float p = __expf(v[g] - mnew); pst[g][r] = p; rs += p; }
#pragma unroll
        for (int sh = 1; sh < 16; sh <<= 1) rs += __shfl_xor(rs, sh, 64);
        l_i[r] = a * l_i[r] + rs;
        m_i[r] = mnew;
        alpha[r] = a;
      }
#pragma unroll
      for (int dt=0; dt<8; dt++)
#pragma unroll
        for (int r=0;r<4;r++) oacc[dt][r] *= alpha[r];
#pragma unroll
      for (int g = 0; g < 4; g++)
#pragma unroll
        for (int r = 0; r < 4; r++)
          sP[wave][(quad*4+r)*72 + g*16 + l15] = f2bf(pst[g][r]);
      // within-wave cross-lane LDS dependency: fence so the reads below see the writes
      asm volatile("s_waitcnt lgkmcnt(0)" ::: "memory");
      short8 pf0 = *(const short8*)&sP[wave][l15*72 + quad*8];
      short8 pf1 = *(const short8*)&sP[wave][l15*72 + 32 + quad*8];
#pragma unroll
      for (int dt = 0; dt < 8; dt++) {
        short8 vf0 = *(const short8*)&sVT[(dt*16 + l15)*72 + quad*8];
        short8 vf1 = *(const short8*)&sVT[(dt*16 + l15)*72 + 32 + quad*8];
        oacc[dt] = __builtin_amdgcn_mfma_f32_16x16x32_bf16(pf0, vf0, oacc[dt], 0,0,0);
        oacc[dt] = __builtin_amdgcn_mfma_f32_16x16x32_bf16(pf1, vf1, oacc[dt], 0,0,0);
      }
    }
  }
  u16* op = O + (size_t)(b*SEQ + q0 + wave*16 + quad*4) * HID + h*DH + l15;
#pragma unroll
  for (int dt=0; dt<8; dt++)
#pragma unroll
    for (int r=0;r<4;r++) {
      float v = oacc[dt][r] / l_i[r];
      op[(size_t)r * HID + dt*16] = f2bf(v);
    }
}

// ---------- in-place: Out += r_o @ Bo ----------
template<typename T>
__global__ __launch_bounds__(256) void out_add_k(const int* __restrict__ fl, int want,
    const float* __restrict__ Ro, const T* __restrict__ Bo, T* __restrict__ Out) {
  if (fl[0] != want) return;
  int c = blockIdx.x * 256 + threadIdx.x;
  int s = blockIdx.y, b = blockIdx.z;
  __shared__ float rr[RANK];
  if (threadIdx.x < RANK) rr[threadIdx.x] = Ro[((size_t)(b*SEQ + s)) * RANK + threadIdx.x];
  __syncthreads();
  size_t row = (size_t)(b*SEQ + s);
  float val = io<T>::ld(Out, row*HID + c);
  const T* bo = Bo + (size_t)b * RANK * HID;
#pragma unroll
  for (int j = 0; j < RANK; j++) val += rr[j] * io<T>::ld(bo, (size_t)j*HID + c);
  io<T>::st(Out, row*HID + c, val);
}

extern "C" void kernel_launch(void* const* d_in, const int* in_sizes, int n_in,
                              void* d_out, int out_size, void* d_ws, size_t ws_size,
                              hipStream_t stream) {
  char* ws = (char*)d_ws;
  const size_t MAT = (size_t)4096 * 4096 * 2;   // one bf16 4096^2 matrix (32 MB)
  // ws layout — peak ~130.1 MB:
  u16* slot0 = (u16*)(ws + 0*MAT);              // W^T staging, then attention output
  u16* slot1 = (u16*)(ws + 1*MAT);              // k_lin, then Wo^T
  u16* slot2 = (u16*)(ws + 2*MAT);              // v_lin
  u16* X_bf  = (u16*)(ws + 3*MAT);              // bf16 hidden_states, then V^T (same elem count)
  float* r_all = (float*)(ws + 4*MAT);
  float* r_o   = (float*)(ws + 4*MAT + (size_t)3*B_REQ*SEQ*RANK*sizeof(float));
  int* dflag   = (int*)(ws + 4*MAT + (size_t)4*B_REQ*SEQ*RANK*sizeof(float));

  u16* q_lin = (u16*)d_out;   // scratch until the O-proj GEMM rewrites d_out
  u16* k_lin = slot1;
  u16* v_lin = slot2;
  u16* attnb = slot0;

  const int NX = B_REQ * SEQ * HID;             // 16.7M elements

  detect_k<<<1, 64, 0, stream>>>((const u16*)d_in[1], dflag);

#define BOTH(call_b, call_f) do { call_b; call_f; } while (0)
  BOTH((convert_k<u16>  <<<8192,256,0,stream>>>(dflag,0,(const u16*)  d_in[0], X_bf, NX)),
       (convert_k<float><<<8192,256,0,stream>>>(dflag,1,(const float*)d_in[0], X_bf, NX)));
  BOTH((lora_r_k<u16>  <<<dim3(SEQ,B_REQ,3),256,0,stream>>>(dflag,0,X_bf,(const u16*)d_in[5],(const u16*)d_in[7],(const u16*)d_in[9],r_all)),
       (lora_r_k<float><<<dim3(SEQ,B_REQ,3),256,0,stream>>>(dflag,1,X_bf,(const float*)d_in[5],(const float*)d_in[7],(const float*)d_in[9],r_all)));

  // QKV projections
  u16* lin[3] = { q_lin, k_lin, v_lin };
  for (int m = 0; m < 3; m++) {
    BOTH((transpose_k<u16>  <<<dim3(64,64),256,0,stream>>>(dflag,0,(const u16*)  d_in[1+m], slot0)),
         (transpose_k<float><<<dim3(64,64),256,0,stream>>>(dflag,1,(const float*)d_in[1+m], slot0)));
    gemm_bt_k<u16><<<dim3(32,32),256,0,stream>>>(dflag,-1, X_bf, slot0, lin[m]);
  }
  BOTH((lora_rope_k<u16>  <<<dim3(SEQ/4,12),256,0,stream>>>(dflag,0,q_lin,k_lin,v_lin,r_all,(const u16*)d_in[6],(const u16*)d_in[8],(const u16*)d_in[10])),
       (lora_rope_k<float><<<dim3(SEQ/4,12),256,0,stream>>>(dflag,1,q_lin,k_lin,v_lin,r_all,(const float*)d_in[6],(const float*)d_in[8],(const float*)d_in[10])));

  // V^T into X_bf (hidden_states no longer needed: lora_r + QKV GEMMs done)
  vtrans_k<<<dim3(SEQ/64,NH,B_REQ),256,0,stream>>>(v_lin, X_bf);

  attn_k<<<dim3(16,NH,B_REQ),256,0,stream>>>(q_lin, k_lin, X_bf, attnb);

  BOTH((lora_r_k<u16>  <<<dim3(SEQ,B_REQ,1),256,0,stream>>>(dflag,0,attnb,(const u16*)d_in[11],(const u16*)d_in[11],(const u16*)d_in[11],r_o)),
       (lora_r_k<float><<<dim3(SEQ,B_REQ,1),256,0,stream>>>(dflag,1,attnb,(const float*)d_in[11],(const float*)d_in[11],(const float*)d_in[11],r_o)));
  BOTH((transpose_k<u16>  <<<dim3(64,64),256,0,stream>>>(dflag,0,(const u16*)  d_in[4], slot1)),
       (transpose_k<float><<<dim3(64,64),256,0,stream>>>(dflag,1,(const float*)d_in[4], slot1)));
  BOTH((gemm_bt_k<u16>  <<<dim3(32,32),256,0,stream>>>(dflag,0, attnb, slot1, (u16*)d_out)),
       (gemm_bt_k<float><<<dim3(32,32),256,0,stream>>>(dflag,1, attnb, slot1, (float*)d_out)));
  BOTH((out_add_k<u16>  <<<dim3(16,SEQ,B_REQ),256,0,stream>>>(dflag,0,r_o,(const u16*)d_in[12],(u16*)d_out)),
       (out_add_k<float><<<dim3(16,SEQ,B_REQ),256,0,stream>>>(dflag,1,r_o,(const float*)d_in[12],(float*)d_out)));
#undef BOTH
}

// Round 3
// 1505.510 us; speedup vs baseline: 1.3563x; 1.1506x over previous
//
#include <hip/hip_runtime.h>
#include <cstdint>

#define HID 4096
#define SEQ 1024
#define B_REQ 4
#define NH 32
#define DH 128
#define RANK 16

typedef unsigned short u16;
typedef __attribute__((ext_vector_type(8))) short short8;
typedef __attribute__((ext_vector_type(8))) unsigned short us8;
typedef __attribute__((ext_vector_type(4))) float f32x4;

static __device__ __forceinline__ float bf2f(u16 u) {
  union { unsigned int i; float f; } v; v.i = ((unsigned int)u) << 16; return v.f;
}
static __device__ __forceinline__ u16 f2bf(float f) {
  union { float f; unsigned int i; } v; v.f = f;
  unsigned int r = v.i + 0x7FFFu + ((v.i >> 16) & 1u);  // RNE
  return (u16)(r >> 16);
}

template<typename T> struct io;
template<> struct io<u16> {
  static __device__ __forceinline__ float ld(const u16* p, size_t i) { return bf2f(p[i]); }
  static __device__ __forceinline__ void st(u16* p, size_t i, float v) { p[i] = f2bf(v); }
};
template<> struct io<float> {
  static __device__ __forceinline__ float ld(const float* p, size_t i) { return p[i]; }
  static __device__ __forceinline__ void st(float* p, size_t i, float v) { p[i] = v; }
};

static __device__ __forceinline__ void ld8f(const u16* p, float* o) {
  us8 v = *(const us8*)p;
#pragma unroll
  for (int i = 0; i < 8; i++) o[i] = bf2f(v[i]);
}
static __device__ __forceinline__ void ld8f(const float* p, float* o) {
  const float4* q = (const float4*)p;
  float4 a = q[0], b = q[1];
  o[0]=a.x; o[1]=a.y; o[2]=a.z; o[3]=a.w; o[4]=b.x; o[5]=b.y; o[6]=b.z; o[7]=b.w;
}

// ---------- dtype probe: bf16 weights never have exponent >= 0xC0; fp32 low halves do ----------
__global__ void detect_k(const u16* __restrict__ w, int* __restrict__ dflag) {
  if (threadIdx.x == 0 && blockIdx.x == 0) {
    int huge = 0;
    for (int i = 0; i < 2048; i++) {
      int e = (w[i] >> 7) & 0xFF;
      if (e >= 0xC0) huge++;
    }
    dflag[0] = (huge > 8) ? 1 : 0;   // 1 => inputs are float32
  }
}

// ---------- convert input matrix to bf16 (identity when already bf16) ----------
template<typename T>
__global__ __launch_bounds__(256) void convert_k(const int* __restrict__ fl, int want,
    const T* __restrict__ src, u16* __restrict__ dst, int n) {
  if (fl[0] != want) return;
  int stride = gridDim.x * blockDim.x;
  for (int i = blockIdx.x * blockDim.x + threadIdx.x; i < n; i += stride)
    dst[i] = f2bf(io<T>::ld(src, i));
}

// ---------- transpose 4096x4096: T[n][k] = bf16(W[k][n]) ----------
template<typename T>
__global__ __launch_bounds__(256) void transpose_k(const int* __restrict__ fl, int want,
    const T* __restrict__ W, u16* __restrict__ Tt) {
  if (fl[0] != want) return;
  __shared__ u16 st[64][68];
  int r0 = blockIdx.y * 64, c0 = blockIdx.x * 64;
  int t = threadIdx.x;
  int r = t >> 2, cb = (t & 3) * 16;
#pragma unroll
  for (int j = 0; j < 16; j++)
    st[r][cb + j] = f2bf(io<T>::ld(W, (size_t)(r0 + r) * HID + c0 + cb + j));
  __syncthreads();
#pragma unroll
  for (int j = 0; j < 4; j++) {
    int cw = cb + j*4;
    ushort4 v;
    v.x = st[cw+0][r]; v.y = st[cw+1][r]; v.z = st[cw+2][r]; v.w = st[cw+3][r];
    *(ushort4*)&Tt[(size_t)(c0 + r) * HID + r0 + cw] = v;
  }
}

// ---------- r[b,s,:] = x_row @ A_b  (K=4096, R=16). z selects A matrix. ----------
template<typename T>
__global__ __launch_bounds__(256) void lora_r_k(const int* __restrict__ fl, int want,
    const u16* __restrict__ X, const T* __restrict__ A0,
    const T* __restrict__ A1, const T* __restrict__ A2, float* __restrict__ R) {
  if (fl[0] != want) return;
  int s = blockIdx.x, b = blockIdx.y, m = blockIdx.z;
  const T* A = (m==0?A0: m==1?A1:A2) + (size_t)b * HID * RANK;
  const u16* x = X + (size_t)(b*SEQ + s) * HID;
  float* r = R + ((size_t)(m*B_REQ + b) * SEQ + s) * RANK;
  int t = threadIdx.x;
  int c = t >> 4;                       // d = c + 16*i  -> A idx = t + 256*i (coalesced)
  float acc = 0.f;
  for (int i = 0; i < 256; i++)
    acc += bf2f(x[c + 16*i]) * io<T>::ld(A, t + 256*i);
  __shared__ float red[256];
  red[t] = acc;
  __syncthreads();
  if (t < 16) {
    float sum = 0.f;
#pragma unroll
    for (int cc = 0; cc < 16; cc++) sum += red[cc*16 + t];
    r[t] = sum;
  }
}

// ================= 256x256 8-phase GEMM: C = A @ BT^T (m201 template, plain HIP) ==========
// 512 thr = 8 waves (2M x 4N), per-wave out 128x64. BK=64, LDS 2buf x (A 32K + B 32K) = 128 KiB.
// Half-tiles issued one per phase into the next buffer; vmcnt(4) per phase => each half-tile
// confirmed by every wave's vmcnt >=1 barrier before its first ds_read (chase verified for
// prologue, steady state, buffer swap, epilogue). Stages always target regions whose last
// reader drained (lgkmcnt(0)) before the preceding barrier.
// T2 swizzle: LDS[R][bc] = G[bc ^ ((R&7)<<4)] -- applied by pre-swizzling the per-lane global
// source (linear global_load_lds dest, rule 21) and XORing the ds_read col.
#define GMFMA __builtin_amdgcn_mfma_f32_16x16x32_bf16
#define WAITV4 asm volatile("s_waitcnt vmcnt(4)" ::: "memory")
#define WAITV0 asm volatile("s_waitcnt vmcnt(0)" ::: "memory")
#define WAITL0 asm volatile("s_waitcnt lgkmcnt(0)" ::: "memory")
#define SBAR   __builtin_amdgcn_s_barrier()
#define SCHED0 __builtin_amdgcn_sched_barrier(0)

#define LDA(BUF,QM,MF,KH) \
  (*(const short8*)((const char*)(&lds[BUF][0][0]) + \
     (((QM)*128 + wm*64 + (MF)*16 + l15) * 128) + (((KH)*64 + quad*16) ^ ((l15 & 7) << 4))))
#define LDB(BUF,QN,NF,KH) \
  (*(const short8*)((const char*)(&lds[BUF][1][0]) + \
     (((QN)*128 + wn*32 + (NF)*16 + l15) * 128) + (((KH)*64 + quad*16) ^ ((l15 & 7) << 4))))

#define MFMA_BLK(QM,QN,A0,A1,A2,A3,B0,B1) \
    acc[(QM)*4+0][(QN)*2+0] = GMFMA(A0,B0,acc[(QM)*4+0][(QN)*2+0],0,0,0); \
    acc[(QM)*4+1][(QN)*2+0] = GMFMA(A1,B0,acc[(QM)*4+1][(QN)*2+0],0,0,0); \
    acc[(QM)*4+2][(QN)*2+0] = GMFMA(A2,B0,acc[(QM)*4+2][(QN)*2+0],0,0,0); \
    acc[(QM)*4+3][(QN)*2+0] = GMFMA(A3,B0,acc[(QM)*4+3][(QN)*2+0],0,0,0); \
    acc[(QM)*4+0][(QN)*2+1] = GMFMA(A0,B1,acc[(QM)*4+0][(QN)*2+1],0,0,0); \
    acc[(QM)*4+1][(QN)*2+1] = GMFMA(A1,B1,acc[(QM)*4+1][(QN)*2+1],0,0,0); \
    acc[(QM)*4+2][(QN)*2+1] = GMFMA(A2,B1,acc[(QM)*4+2][(QN)*2+1],0,0,0); \
    acc[(QM)*4+3][(QN)*2+1] = GMFMA(A3,B1,acc[(QM)*4+3][(QN)*2+1],0,0,0);

#define PHASE(BUF, QM, QN, STAGE) do { \
    short8 a00=LDA(BUF,QM,0,0), a10=LDA(BUF,QM,1,0), a20=LDA(BUF,QM,2,0), a30=LDA(BUF,QM,3,0); \
    short8 a01=LDA(BUF,QM,0,1), a11=LDA(BUF,QM,1,1), a21=LDA(BUF,QM,2,1), a31=LDA(BUF,QM,3,1); \
    short8 b00=LDB(BUF,QN,0,0), b10=LDB(BUF,QN,1,0); \
    short8 b01=LDB(BUF,QN,0,1), b11=LDB(BUF,QN,1,1); \
    STAGE; \
    WAITV4; SCHED0; \
    SBAR; \
    WAITL0; SCHED0; \
    __builtin_amdgcn_s_setprio(1); \
    MFMA_BLK(QM,QN,a00,a10,a20,a30,b00,b10) \
    MFMA_BLK(QM,QN,a01,a11,a21,a31,b01,b11) \
    __builtin_amdgcn_s_setprio(0); \
    SBAR; \
  } while (0)

#define PHASE_TAIL(BUF, QM, QN) do { \
    short8 a00=LDA(BUF,QM,0,0), a10=LDA(BUF,QM,1,0), a20=LDA(BUF,QM,2,0), a30=LDA(BUF,QM,3,0); \
    short8 a01=LDA(BUF,QM,0,1), a11=LDA(BUF,QM,1,1), a21=LDA(BUF,QM,2,1), a31=LDA(BUF,QM,3,1); \
    short8 b00=LDB(BUF,QN,0,0), b10=LDB(BUF,QN,1,0); \
    short8 b01=LDB(BUF,QN,0,1), b11=LDB(BUF,QN,1,1); \
    WAITL0; SCHED0; \
    __builtin_amdgcn_s_setprio(1); \
    MFMA_BLK(QM,QN,a00,a10,a20,a30,b00,b10) \
    MFMA_BLK(QM,QN,a01,a11,a21,a31,b01,b11) \
    __builtin_amdgcn_s_setprio(0); \
  } while (0)

template<typename TOUT>
__global__ __launch_bounds__(512, 2) void gemm256_k(const int* __restrict__ fl, int want,
    const u16* __restrict__ A, const u16* __restrict__ BT, TOUT* __restrict__ C) {
  if (want >= 0 && fl[0] != want) return;
  __shared__ u16 lds[2][2][256*64];     // [buf][A/B][row*64], 128 KiB
  const int tid = threadIdx.x, lane = tid & 63, wave = tid >> 6;
  const int l15 = lane & 15, quad = lane >> 4;
  const int wm = wave >> 2, wn = wave & 3;
  // bijective XCD swizzle: 256 blocks, 8 XCDs, 32/XCD
  int bid = blockIdx.x;
  int swz = (bid & 7) * 32 + (bid >> 3);
  const int m0 = (swz >> 4) * 256, n0 = (swz & 15) * 256;
  // staging geometry: per issue 512 thr x 16B = 64 rows x 128B; wave-uniform LDS dest,
  // per-lane inverse-swizzled global source (rule 21).
  const int r = tid >> 3;                                    // 0..63 row within issue
  const int ce = ((((tid & 7) * 16) ^ ((r & 7) << 4)) >> 1); // logical elem col 0..63

  auto stA = [&](int nb, int ht, int kt) {
    const u16* s0 = A + (size_t)(m0 + ht*64 + r)       * HID + kt*64 + ce;
    const u16* s1 = A + (size_t)(m0 + 128 + ht*64 + r) * HID + kt*64 + ce;
    u16* d0 = &lds[nb][0][(ht*128 + wave*8) * 64];
    u16* d1 = &lds[nb][0][(ht*128 + 64 + wave*8) * 64];
    __builtin_amdgcn_global_load_lds((const __attribute__((address_space(1))) void*)s0,
        (__attribute__((address_space(3))) void*)d0, 16, 0, 0);
    __builtin_amdgcn_global_load_lds((const __attribute__((address_space(1))) void*)s1,
        (__attribute__((address_space(3))) void*)d1, 16, 0, 0);
  };
  auto stB = [&](int nb, int qn, int kt) {
    const u16* s0 = BT + (size_t)(n0 + (r>>5)*64 + qn*32 + (r&31))       * HID + kt*64 + ce;
    const u16* s1 = BT + (size_t)(n0 + 128 + (r>>5)*64 + qn*32 + (r&31)) * HID + kt*64 + ce;
    u16* d0 = &lds[nb][1][(qn*128 + wave*8) * 64];
    u16* d1 = &lds[nb][1][(qn*128 + 64 + wave*8) * 64];
    __builtin_amdgcn_global_load_lds((const __attribute__((address_space(1))) void*)s0,
        (__attribute__((address_space(3))) void*)d0, 16, 0, 0);
    __builtin_amdgcn_global_load_lds((const __attribute__((address_space(1))) void*)s1,
        (__attribute__((address_space(3))) void*)d1, 16, 0, 0);
  };

  f32x4 acc[8][4];
  f32x4 zero = {0.f,0.f,0.f,0.f};
#pragma unroll
  for (int i=0;i<8;i++)
#pragma unroll
    for (int j=0;j<4;j++) acc[i][j] = zero;

  // prologue: tile 0 into buf0; wait Ah0,Bh0 (oldest 4 loads of 8)
  stA(0,0,0); stB(0,0,0); stA(0,1,0); stB(0,1,0);
  WAITV4; SCHED0;
  SBAR;

  // main: tiles 0..61, x2 unroll (static buf); each phase stages one half-tile ahead
  for (int tt = 0; tt < 31; ++tt) {
    int kn = tt*2 + 1;
    PHASE(0,0,0, stA(1,0,kn)); PHASE(0,1,0, stB(1,0,kn));
    PHASE(0,0,1, stA(1,1,kn)); PHASE(0,1,1, stB(1,1,kn));
    PHASE(1,0,0, stA(0,0,kn+1)); PHASE(1,1,0, stB(0,0,kn+1));
    PHASE(1,0,1, stA(0,1,kn+1)); PHASE(1,1,1, stB(0,1,kn+1));
  }
  // tile 62 (buf0), staging tile 63 into buf1
  PHASE(0,0,0, stA(1,0,63)); PHASE(0,1,0, stB(1,0,63));
  PHASE(0,0,1, stA(1,1,63)); PHASE(0,1,1, stB(1,1,63));
  // epilogue drain + peeled tile 63 (buf1), no further staging
  WAITV0; SCHED0;
  SBAR;
  PHASE_TAIL(1,0,0); PHASE_TAIL(1,1,0); PHASE_TAIL(1,0,1); PHASE_TAIL(1,1,1);

  // C write: frag (mfi,nfi) -> row m0+wm*128+(mfi>>2)*64+(mfi&3)*16+quad*4+rr,
  //                            col n0+wn*64+(nfi>>1)*32+(nfi&1)*16+l15
  const int crow = m0 + wm*128 + quad*4;
  const int ccol = n0 + wn*64 + l15;
#pragma unroll
  for (int mfi = 0; mfi < 8; mfi++)
#pragma unroll
    for (int nfi = 0; nfi < 4; nfi++)
#pragma unroll
      for (int rr = 0; rr < 4; rr++)
        io<TOUT>::st(C, (size_t)(crow + (mfi>>2)*64 + (mfi&3)*16 + rr) * HID
                        + ccol + (nfi>>1)*32 + (nfi&1)*16, acc[mfi][nfi][rr]);
}

// ---------- in-place bf16: val = lin + r@B ; rope for kind 0,1 ; plain for kind 2 ----------
template<typename T>
__global__ __launch_bounds__(256) void lora_rope_k(const int* __restrict__ fl, int want,
    u16* __restrict__ Qb, u16* __restrict__ Kb, u16* __restrict__ Vb,
    const float* __restrict__ R,
    const T* __restrict__ Bq, const T* __restrict__ Bk, const T* __restrict__ Bv) {
  if (fl[0] != want) return;
  int s0 = blockIdx.x * 4;
  int z = blockIdx.y; int kind = z >> 2, b = z & 3;
  u16* Ob = kind==0?Qb: kind==1?Kb:Vb;
  const T* Bm = (kind==0?Bq: kind==1?Bk:Bv) + (size_t)b * RANK * HID;
  int t = threadIdx.x;
  int h = t >> 3, d0 = (t & 7) * 8;
  int col0 = h*DH + d0, col1 = col0 + 64;
  __shared__ float rr[4][RANK];
  if (t < 64)
    rr[t>>4][t&15] = R[((size_t)(kind*B_REQ + b) * SEQ + s0 + (t>>4)) * RANK + (t&15)];
  __syncthreads();
  float v0[4][8], v1[4][8];
  size_t base = (size_t)(b*SEQ + s0) * HID;
#pragma unroll
  for (int si = 0; si < 4; si++) {
    us8 a = *(const us8*)&Ob[base + (size_t)si*HID + col0];
    us8 c = *(const us8*)&Ob[base + (size_t)si*HID + col1];
#pragma unroll
    for (int i = 0; i < 8; i++) { v0[si][i] = bf2f(a[i]); v1[si][i] = bf2f(c[i]); }
  }
#pragma unroll 4
  for (int j = 0; j < RANK; j++) {
    float b0[8], b1[8];
    ld8f(Bm + (size_t)j*HID + col0, b0);
    ld8f(Bm + (size_t)j*HID + col1, b1);
#pragma unroll
    for (int si = 0; si < 4; si++) {
      float rj = rr[si][j];
#pragma unroll
      for (int i = 0; i < 8; i++) { v0[si][i] += rj*b0[i]; v1[si][i] += rj*b1[i]; }
    }
  }
  if (kind == 2) {
#pragma unroll
    for (int si = 0; si < 4; si++) {
      us8 a, c;
#pragma unroll
      for (int i = 0; i < 8; i++) { a[i] = f2bf(v0[si][i]); c[i] = f2bf(v1[si][i]); }
      *(us8*)&Ob[base + (size_t)si*HID + col0] = a;
      *(us8*)&Ob[base + (size_t)si*HID + col1] = c;
    }
    return;
  }
  float fr[8];
#pragma unroll
  for (int i = 0; i < 8; i++)
    fr[i] = exp2f((float)(d0 + i) * (-13.287712379549449f / 64.f));
#pragma unroll
  for (int si = 0; si < 4; si++) {
    float sa = (float)(s0 + si);
    us8 a, c;
#pragma unroll
    for (int i = 0; i < 8; i++) {
      float sn, cs;
      sincosf(sa * fr[i], &sn, &cs);
      a[i] = f2bf(v0[si][i]*cs - v1[si][i]*sn);
      c[i] = f2bf(v1[si][i]*cs + v0[si][i]*sn);
    }
    *(us8*)&Ob[base + (size_t)si*HID + col0] = a;
    *(us8*)&Ob[base + (size_t)si*HID + col1] = c;
  }
}

// ---------- V^T: VT[(b*NH+h)*DH + d][s] = V[b*SEQ+s][h*DH+d] ----------
__global__ __launch_bounds__(256) void vtrans_k(const u16* __restrict__ V, u16* __restrict__ VT) {
  int st = blockIdx.x, h = blockIdx.y, b = blockIdx.z;
  int s0 = st * 64;
  __shared__ u16 tmp[64][136];
  int t = threadIdx.x;
  int sr = t >> 2, c0 = (t & 3) * 32;
  const u16* vp = V + (size_t)(b*SEQ + s0 + sr) * HID + h*DH + c0;
#pragma unroll
  for (int j = 0; j < 4; j++)
    *(us8*)&tmp[sr][c0 + j*8] = *(const us8*)(vp + j*8);
  __syncthreads();
  int d = t >> 1, so = (t & 1) * 32;
  u16* op = VT + ((size_t)(b*NH + h) * DH + d) * SEQ + s0 + so;
#pragma unroll
  for (int j = 0; j < 4; j++) {
    us8 v;
#pragma unroll
    for (int i = 0; i < 8; i++) ((u16*)&v)[i] = tmp[so + j*8 + i][d];
    *(us8*)(op + j*8) = v;
  }
}

// ---------- flash attention: block = (b, h, 64 q rows), 4 waves x 16 q rows, KVBLK=64 ----------
__global__ __launch_bounds__(256) void attn_k(
    const u16* __restrict__ Q, const u16* __restrict__ K, const u16* __restrict__ VT,
    u16* __restrict__ O) {
  int qb = (int)gridDim.x - 1 - (int)blockIdx.x;
  int h = blockIdx.y, b = blockIdx.z;
  int q0 = qb * 64;
  int tid = threadIdx.x, lane = tid & 63, wave = tid >> 6;
  int l15 = lane & 15, quad = lane >> 4;
  __shared__ u16 sK[64*136];
  __shared__ u16 sVT[128*72];
  __shared__ u16 sP[4][16*72];
  short8 qf[4];
  {
    const u16* qp = Q + (size_t)(b*SEQ + q0 + wave*16 + l15) * HID + h*DH + quad*8;
#pragma unroll
    for (int c = 0; c < 4; c++) qf[c] = *(const short8*)(qp + c*32);
  }
  f32x4 zero = {0.f,0.f,0.f,0.f};
  f32x4 oacc[8];
#pragma unroll
  for (int i=0;i<8;i++) oacc[i] = zero;
  float m_i[4], l_i[4];
#pragma unroll
  for (int r=0;r<4;r++){ m_i[r] = -1e30f; l_i[r] = 0.f; }
  int krow = tid >> 2, kcol = (tid & 3) * 32;
  int vrow = tid >> 1, vcol = (tid & 1) * 32;
  const u16* kbase = K + (size_t)(b*SEQ) * HID + h*DH;
  const u16* vbase = VT + (size_t)(b*NH + h) * DH * SEQ;
  int nkt = qb + 1;
  for (int kt = 0; kt < nkt; kt++) {
    int k0 = kt * 64;
    __syncthreads();
    {
      const u16* kp = kbase + (size_t)(k0 + krow) * HID + kcol;
#pragma unroll
      for (int j = 0; j < 4; j++)
        *(us8*)&sK[krow*136 + kcol + j*8] = *(const us8*)(kp + j*8);
      const u16* vp = vbase + (size_t)vrow * SEQ + k0 + vcol;
#pragma unroll
      for (int j = 0; j < 4; j++)
        *(us8*)&sVT[vrow*72 + vcol + j*8] = *(const us8*)(vp + j*8);
    }
    __syncthreads();
    int q_hi = q0 + wave*16 + 15;
    if (k0 <= q_hi) {
      f32x4 sc4[4];
#pragma unroll
      for (int g=0;g<4;g++) sc4[g] = zero;
#pragma unroll
      for (int c = 0; c < 4; c++) {
#pragma unroll
        for (int g = 0; g < 4; g++) {
          short8 kf = *(const short8*)&sK[(g*16 + l15)*136 + c*32 + quad*8];
          sc4[g] = __builtin_amdgcn_mfma_f32_16x16x32_bf16(qf[c], kf, sc4[g], 0,0,0);
        }
      }
      const float scale = 0.08838834764831845f;   // 1/sqrt(128)
      float alpha[4], pst[4][4];
#pragma unroll
      for (int r = 0; r < 4; r++) {
        int q_abs = q0 + wave*16 + quad*4 + r;
        float v[4];
#pragma unroll
        for (int g = 0; g < 4; g++) {
          v[g] = sc4[g][r] * scale;
          if (k0 + g*16 + l15 > q_abs) v[g] = -1e30f;
        }
        float mx = fmaxf(fmaxf(v[0],v[1]), fmaxf(v[2],v[3]));
#pragma unroll
        for (int sh = 1; sh < 16; sh <<= 1) mx = fmaxf(mx, __shfl_xor(mx, sh, 64));
        float mnew = fmaxf(m_i[r], mx);
        float a = __expf(m_i[r] - mnew);
        float rs = 0.f;
#pragma unroll
        for (int g = 0; g < 4; g++) { float p = __expf(v[g] - mnew); pst[g][r] = p; rs += p; }
#pragma unroll
        for (int sh = 1; sh < 16; sh <<= 1) rs += __shfl_xor(rs, sh, 64);
        l_i[r] = a * l_i[r] + rs;
        m_i[r] = mnew;
        alpha[r] = a;
      }
#pragma unroll
      for (int dt=0; dt<8; dt++)
#pragma unroll
        for (int r=0;r<4;r++) oacc[dt][r] *= alpha[r];
#pragma unroll
      for (int g = 0; g < 4; g++)
#pragma unroll
        for (int r = 0; r < 4; r++)
          sP[wave][(quad*4+r)*72 + g*16 + l15] = f2bf(pst[g][r]);
      asm volatile("s_waitcnt lgkmcnt(0)" ::: "memory");
      short8 pf0 = *(const short8*)&sP[wave][l15*72 + quad*8];
      short8 pf1 = *(const short8*)&sP[wave][l15*72 + 32 + quad*8];
#pragma unroll
      for (int dt = 0; dt < 8; dt++) {
        short8 vf0 = *(const short8*)&sVT[(dt*16 + l15)*72 + quad*8];
        short8 vf1 = *(const short8*)&sVT[(dt*16 + l15)*72 + 32 + quad*8];
        oacc[dt] = __builtin_amdgcn_mfma_f32_16x16x32_bf16(pf0, vf0, oacc[dt], 0,0,0);
        oacc[dt] = __builtin_amdgcn_mfma_f32_16x16x32_bf16(pf1, vf1, oacc[dt], 0,0,0);
      }
    }
  }
  u16* op = O + (size_t)(b*SEQ + q0 + wave*16 + quad*4) * HID + h*DH + l15;
#pragma unroll
  for (int dt=0; dt<8; dt++)
#pragma unroll
    for (int r=0;r<4;r++) {
      float v = oacc[dt][r] / l_i[r];
      op[(size_t)r * HID + dt*16] = f2bf(v);
    }
}

// ---------- in-place: Out += r_o @ Bo ----------
template<typename T>
__global__ __launch_bounds__(256) void out_add_k(const int* __restrict__ fl, int want,
    const float* __restrict__ Ro, const T* __restrict__ Bo, T* __restrict__ Out) {
  if (fl[0] != want) return;
  int c = blockIdx.x * 256 + threadIdx.x;
  int s = blockIdx.y, b = blockIdx.z;
  __shared__ float rr[RANK];
  if (threadIdx.x < RANK) rr[threadIdx.x] = Ro[((size_t)(b*SEQ + s)) * RANK + threadIdx.x];
  __syncthreads();
  size_t row = (size_t)(b*SEQ + s);
  float val = io<T>::ld(Out, row*HID + c);
  const T* bo = Bo + (size_t)b * RANK * HID;
#pragma unroll
  for (int j = 0; j < RANK; j++) val += rr[j] * io<T>::ld(bo, (size_t)j*HID + c);
  io<T>::st(Out, row*HID + c, val);
}

extern "C" void kernel_launch(void* const* d_in, const int* in_sizes, int n_in,
                              void* d_out, int out_size, void* d_ws, size_t ws_size,
                              hipStream_t stream) {
  char* ws = (char*)d_ws;
  const size_t MAT = (size_t)4096 * 4096 * 2;   // one bf16 4096^2 matrix (32 MB)
  u16* slot0 = (u16*)(ws + 0*MAT);              // W^T staging, then attention output
  u16* slot1 = (u16*)(ws + 1*MAT);              // k_lin, then Wo^T
  u16* slot2 = (u16*)(ws + 2*MAT);              // v_lin
  u16* X_bf  = (u16*)(ws + 3*MAT);              // bf16 hidden_states, then V^T
  float* r_all = (float*)(ws + 4*MAT);
  float* r_o   = (float*)(ws + 4*MAT + (size_t)3*B_REQ*SEQ*RANK*sizeof(float));
  int* dflag   = (int*)(ws + 4*MAT + (size_t)4*B_REQ*SEQ*RANK*sizeof(float));

  u16* q_lin = (u16*)d_out;   // scratch until the O-proj GEMM rewrites d_out
  u16* k_lin = slot1;
  u16* v_lin = slot2;
  u16* attnb = slot0;

  const int NX = B_REQ * SEQ * HID;             // 16.7M elements

  detect_k<<<1, 64, 0, stream>>>((const u16*)d_in[1], dflag);

#define BOTH(call_b, call_f) do { call_b; call_f; } while (0)
  BOTH((convert_k<u16>  <<<8192,256,0,stream>>>(dflag,0,(const u16*)  d_in[0], X_bf, NX)),
       (convert_k<float><<<8192,256,0,stream>>>(dflag,1,(const float*)d_in[0], X_bf, NX)));
  BOTH((lora_r_k<u16>  <<<dim3(SEQ,B_REQ,3),256,0,stream>>>(dflag,0,X_bf,(const u16*)d_in[5],(const u16*)d_in[7],(const u16*)d_in[9],r_all)),
       (lora_r_k<float><<<dim3(SEQ,B_REQ,3),256,0,stream>>>(dflag,1,X_bf,(const float*)d_in[5],(const float*)d_in[7],(const float*)d_in[9],r_all)));

  // QKV projections
  u16* lin[3] = { q_lin, k_lin, v_lin };
  for (int m = 0; m < 3; m++) {
    BOTH((transpose_k<u16>  <<<dim3(64,64),256,0,stream>>>(dflag,0,(const u16*)  d_in[1+m], slot0)),
         (transpose_k<float><<<dim3(64,64),256,0,stream>>>(dflag,1,(const float*)d_in[1+m], slot0)));
    gemm256_k<u16><<<256,512,0,stream>>>(dflag,-1, X_bf, slot0, lin[m]);
  }
  BOTH((lora_rope_k<u16>  <<<dim3(SEQ/4,12),256,0,stream>>>(dflag,0,q_lin,k_lin,v_lin,r_all,(const u16*)d_in[6],(const u16*)d_in[8],(const u16*)d_in[10])),
       (lora_rope_k<float><<<dim3(SEQ/4,12),256,0,stream>>>(dflag,1,q_lin,k_lin,v_lin,r_all,(const float*)d_in[6],(const float*)d_in[8],(const float*)d_in[10])));

  // V^T into X_bf (hidden_states no longer needed)
  vtrans_k<<<dim3(SEQ/64,NH,B_REQ),256,0,stream>>>(v_lin, X_bf);

  attn_k<<<dim3(16,NH,B_REQ),256,0,stream>>>(q_lin, k_lin, X_bf, attnb);

  BOTH((lora_r_k<u16>  <<<dim3(SEQ,B_REQ,1),256,0,stream>>>(dflag,0,attnb,(const u16*)d_in[11],(const u16*)d_in[11],(const u16*)d_in[11],r_o)),
       (lora_r_k<float><<<dim3(SEQ,B_REQ,1),256,0,stream>>>(dflag,1,attnb,(const float*)d_in[11],(const float*)d_in[11],(const float*)d_in[11],r_o)));
  BOTH((transpose_k<u16>  <<<dim3(64,64),256,0,stream>>>(dflag,0,(const u16*)  d_in[4], slot1)),
       (transpose_k<float><<<dim3(64,64),256,0,stream>>>(dflag,1,(const float*)d_in[4], slot1)));
  BOTH((gemm256_k<u16>  <<<256,512,0,stream>>>(dflag,0, attnb, slot1, (u16*)d_out)),
       (gemm256_k<float><<<256,512,0,stream>>>(dflag,1, attnb, slot1, (float*)d_out)));
  BOTH((out_add_k<u16>  <<<dim3(16,SEQ,B_REQ),256,0,stream>>>(dflag,0,r_o,(const u16*)d_in[12],(u16*)d_out)),
       (out_add_k<float><<<dim3(16,SEQ,B_REQ),256,0,stream>>>(dflag,1,r_o,(const float*)d_in[12],(float*)d_out)));
#undef BOTH
}